// Round 1
// baseline (236.684 us; speedup 1.0000x reference)
//
#include <hip/hip_runtime.h>
#include <cstdint>
#include <cstddef>

typedef __bf16 bf16;
typedef __bf16 bf16x8 __attribute__((ext_vector_type(8)));
typedef float f32x4 __attribute__((ext_vector_type(4)));

#define DEVINL __device__ __forceinline__

static constexpr int Tn   = 1024;
static constexpr int DIM  = 1024;
static constexpr int NH   = 16;
static constexpr int DH   = 64;
static constexpr int QKVN = 3072;

DEVINL void g2l16(const void* g, void* l) {
  __builtin_amdgcn_global_load_lds(
      (const __attribute__((address_space(1))) void*)g,
      (__attribute__((address_space(3))) void*)l, 16, 0, 0);
}

// ---------------- pre/post utility kernels ----------------

__global__ void k_f32_to_bf16(const float* __restrict__ in, bf16* __restrict__ out, int n4) {
  int i = blockIdx.x * blockDim.x + threadIdx.x;
  if (i >= n4) return;
  float4 v = reinterpret_cast<const float4*>(in)[i];
  bf16 o[4] = {(bf16)v.x, (bf16)v.y, (bf16)v.z, (bf16)v.w};
  reinterpret_cast<uint2*>(out)[i] = *reinterpret_cast<uint2*>(o);
}

// W[K][N] f32 -> Wt[N][K] bf16   (block 32x8, grid (N/32, K/32))
__global__ void k_transpose_w(const float* __restrict__ in, bf16* __restrict__ out, int K, int N) {
  __shared__ float tile[32][33];
  int n0 = blockIdx.x * 32, k0 = blockIdx.y * 32;
  int tx = threadIdx.x, ty = threadIdx.y;
#pragma unroll
  for (int j = 0; j < 32; j += 8)
    tile[ty + j][tx] = in[(size_t)(k0 + ty + j) * N + n0 + tx];
  __syncthreads();
#pragma unroll
  for (int j = 0; j < 32; j += 8)
    out[(size_t)(n0 + ty + j) * K + k0 + tx] = (bf16)tile[tx][ty + j];
}

// RoPE in-place on q,k sections of qkv (B,T,3*1024) bf16. 2,097,152 threads, one pair each.
__global__ void k_rope(bf16* __restrict__ qkv) {
  int idx = blockIdx.x * 256 + threadIdx.x;
  int i = idx & 15;
  int h = (idx >> 4) & 15;
  int w = (idx >> 8) & 1;
  int t = (idx >> 9) & 1023;
  int b = idx >> 19;
  // inv_freq = 10000^(-2i/32) = 2^(-2i/32 * log2(10000))
  float inv = exp2f(-(float)(2 * i) * (13.287712379549449f / 32.0f));
  float ang = (float)t * inv;
  float sn, cs;
  sincosf(ang, &sn, &cs);
  size_t base = ((size_t)(b * Tn + t)) * QKVN + (size_t)w * DIM + h * DH + 2 * i;
  float x1 = (float)qkv[base], x2 = (float)qkv[base + 1];
  qkv[base]     = (bf16)(x1 * cs - x2 * sn);
  qkv[base + 1] = (bf16)(x2 * cs + x1 * sn);
}

// V section of qkv -> vt[b][h][d][t]  (block 32x8, grid (T/32, DH/32, B*NH))
__global__ void k_transpose_v(const bf16* __restrict__ qkv, bf16* __restrict__ vt) {
  __shared__ bf16 tile[32][33];
  int t0 = blockIdx.x * 32, d0 = blockIdx.y * 32;
  int bh = blockIdx.z;
  int b = bh >> 4, h = bh & 15;
  int tx = threadIdx.x, ty = threadIdx.y;
#pragma unroll
  for (int j = 0; j < 32; j += 8)
    tile[ty + j][tx] = qkv[((size_t)(b * Tn + t0 + ty + j)) * QKVN + 2 * DIM + h * DH + d0 + tx];
  __syncthreads();
#pragma unroll
  for (int j = 0; j < 32; j += 8)
    vt[((size_t)(bh * DH + d0 + ty + j)) * Tn + t0 + tx] = tile[tx][ty + j];
}

// ---------------- MFMA GEMM: C[M,N] = A[M,K] * Bt[N,K]^T ----------------
// 128x128 tile, BK=64, 256 threads (4 waves, each 64x64).
// LDS chunk-XOR swizzle: physical 16B-chunk c of row r holds logical chunk c^(r&7).
template <bool F32OUT>
__global__ __launch_bounds__(256) void k_gemm_bt(
    const bf16* __restrict__ A, const bf16* __restrict__ Bt,
    void* __restrict__ Cp, int M, int N, int K) {
  __shared__ bf16 As[128 * 64];
  __shared__ bf16 Bs[128 * 64];
  const int tid  = threadIdx.x;
  const int wave = tid >> 6, lane = tid & 63;
  const int lrow = lane & 15, quad = lane >> 4;
  const int m0 = blockIdx.y * 128, n0 = blockIdx.x * 128;
  const int wm = (wave >> 1) * 64, wn = (wave & 1) * 64;

  f32x4 acc[4][4];
#pragma unroll
  for (int mi = 0; mi < 4; mi++)
#pragma unroll
    for (int ni = 0; ni < 4; ni++) acc[mi][ni] = 0.f;

  for (int k0 = 0; k0 < K; k0 += 64) {
    __syncthreads();
#pragma unroll
    for (int i = 0; i < 4; i++) {
      int li = i * 256 + tid;
      int row = li >> 3, c = li & 7;
      int gc = c ^ (row & 7);
      g2l16(A + (size_t)(m0 + row) * K + k0 + gc * 8, As + li * 8);
    }
#pragma unroll
    for (int i = 0; i < 4; i++) {
      int li = i * 256 + tid;
      int row = li >> 3, c = li & 7;
      int gc = c ^ (row & 7);
      g2l16(Bt + (size_t)(n0 + row) * K + k0 + gc * 8, Bs + li * 8);
    }
    __syncthreads();
#pragma unroll
    for (int ki = 0; ki < 2; ki++) {
      bf16x8 af[4], bfr[4];
#pragma unroll
      for (int mi = 0; mi < 4; mi++) {
        int r = wm + mi * 16 + lrow;
        int pc = (ki * 4 + quad) ^ (r & 7);
        af[mi] = *reinterpret_cast<const bf16x8*>(As + r * 64 + pc * 8);
      }
#pragma unroll
      for (int ni = 0; ni < 4; ni++) {
        int r = wn + ni * 16 + lrow;
        int pc = (ki * 4 + quad) ^ (r & 7);
        bfr[ni] = *reinterpret_cast<const bf16x8*>(Bs + r * 64 + pc * 8);
      }
#pragma unroll
      for (int mi = 0; mi < 4; mi++)
#pragma unroll
        for (int ni = 0; ni < 4; ni++)
          acc[mi][ni] = __builtin_amdgcn_mfma_f32_16x16x32_bf16(af[mi], bfr[ni], acc[mi][ni], 0, 0, 0);
    }
  }

#pragma unroll
  for (int mi = 0; mi < 4; mi++)
#pragma unroll
    for (int ni = 0; ni < 4; ni++) {
      int col = n0 + wn + ni * 16 + lrow;
#pragma unroll
      for (int r = 0; r < 4; r++) {
        int row = m0 + wm + mi * 16 + quad * 4 + r;
        float v = acc[mi][ni][r];
        if (F32OUT)
          reinterpret_cast<float*>(Cp)[(size_t)row * N + col] = v;
        else
          reinterpret_cast<bf16*>(Cp)[(size_t)row * N + col] = (bf16)v;
      }
    }
}

// ---------------- causal flash attention ----------------
// grid (T/64, B*NH), 256 threads. Each wave: 16 q rows; block: 64 q rows.
__global__ __launch_bounds__(256) void k_attn(
    const bf16* __restrict__ qkv, const bf16* __restrict__ vt,
    bf16* __restrict__ ao) {
  __shared__ bf16 Ks[32 * 64];        // [key][d], chunk-swizzled by key&7
  __shared__ bf16 Vs[64 * 32];        // [d][key], chunk-swizzled by (d>>1)&3
  __shared__ bf16 Ps[4][16 * 32];     // per-wave P, chunk-swizzled by (m>>1)&3

  const int tid  = threadIdx.x;
  const int wave = tid >> 6, lane = tid & 63;
  const int lrow = lane & 15, quad = lane >> 4;
  const int bh = blockIdx.y, b = bh >> 4, h = bh & 15;
  const int q0 = blockIdx.x * 64;
  const int qw = q0 + wave * 16;
  const size_t qbase = (size_t)b * Tn * QKVN;

  bf16x8 qf[2];
  {
    const bf16* qp = qkv + qbase + (size_t)(qw + lrow) * QKVN + h * DH;
    qf[0] = *reinterpret_cast<const bf16x8*>(qp + quad * 8);
    qf[1] = *reinterpret_cast<const bf16x8*>(qp + 32 + quad * 8);
  }

  f32x4 oa[4];
#pragma unroll
  for (int g = 0; g < 4; g++) oa[g] = 0.f;
  float mi[4] = {-1e30f, -1e30f, -1e30f, -1e30f};
  float li[4] = {0.f, 0.f, 0.f, 0.f};
  const float SC = 0.125f * 1.44269504088896f;  // 1/sqrt(dh) * log2(e)

  const int ktiles = (q0 + 64) >> 5;
  for (int kt = 0; kt < ktiles; kt++) {
    const int k0 = kt << 5;
    __syncthreads();
    {
      int key = tid >> 3, c = tid & 7, gc = c ^ (key & 7);
      g2l16(qkv + qbase + (size_t)(k0 + key) * QKVN + DIM + h * DH + gc * 8, Ks + tid * 8);
      int d = tid >> 2, c2 = tid & 3, gc2 = c2 ^ ((d >> 1) & 3);
      g2l16(vt + ((size_t)bh * DH + d) * Tn + k0 + gc2 * 8, Vs + tid * 8);
    }
    __syncthreads();

    f32x4 s0 = 0.f, s1 = 0.f;
#pragma unroll
    for (int ki = 0; ki < 2; ki++) {
      int lc = ki * 4 + quad;
      int keyA = lrow;
      bf16x8 kf0 = *reinterpret_cast<const bf16x8*>(Ks + keyA * 64 + ((lc ^ (keyA & 7)) << 3));
      s0 = __builtin_amdgcn_mfma_f32_16x16x32_bf16(qf[ki], kf0, s0, 0, 0, 0);
      int keyB = 16 + lrow;
      bf16x8 kf1 = *reinterpret_cast<const bf16x8*>(Ks + keyB * 64 + ((lc ^ (keyB & 7)) << 3));
      s1 = __builtin_amdgcn_mfma_f32_16x16x32_bf16(qf[ki], kf1, s1, 0, 0, 0);
    }

    float pr0[4], pr1[4];
#pragma unroll
    for (int r = 0; r < 4; r++) {
      int qi = qw + quad * 4 + r;
      float sv0 = (k0 + lrow      <= qi) ? s0[r] * SC : -1e30f;
      float sv1 = (k0 + 16 + lrow <= qi) ? s1[r] * SC : -1e30f;
      float tm = fmaxf(sv0, sv1);
      tm = fmaxf(tm, __shfl_xor(tm, 1, 64));
      tm = fmaxf(tm, __shfl_xor(tm, 2, 64));
      tm = fmaxf(tm, __shfl_xor(tm, 4, 64));
      tm = fmaxf(tm, __shfl_xor(tm, 8, 64));
      float mn = fmaxf(mi[r], tm);
      float alpha = exp2f(mi[r] - mn);
      mi[r] = mn;
      float p0 = exp2f(sv0 - mn);
      float p1 = exp2f(sv1 - mn);
      pr0[r] = p0; pr1[r] = p1;
      float rs = p0 + p1;
      rs += __shfl_xor(rs, 1, 64);
      rs += __shfl_xor(rs, 2, 64);
      rs += __shfl_xor(rs, 4, 64);
      rs += __shfl_xor(rs, 8, 64);
      li[r] = li[r] * alpha + rs;
      oa[0][r] *= alpha; oa[1][r] *= alpha; oa[2][r] *= alpha; oa[3][r] *= alpha;
    }

    // P (C-layout) -> LDS -> A-layout
#pragma unroll
    for (int r = 0; r < 4; r++) {
      int m = quad * 4 + r;
      int ph = (m >> 1) & 3;
      int nA = lrow;
      Ps[wave][m * 32 + ((((nA >> 3)) ^ ph) << 3) + (nA & 7)] = (bf16)pr0[r];
      int nB = 16 + lrow;
      Ps[wave][m * 32 + ((((nB >> 3)) ^ ph) << 3) + (nB & 7)] = (bf16)pr1[r];
    }
    bf16x8 pf = *reinterpret_cast<const bf16x8*>(
        Ps[wave] + lrow * 32 + ((quad ^ ((lrow >> 1) & 3)) << 3));
#pragma unroll
    for (int g = 0; g < 4; g++) {
      int d = g * 16 + lrow;
      bf16x8 vf = *reinterpret_cast<const bf16x8*>(
          Vs + d * 32 + ((quad ^ ((d >> 1) & 3)) << 3));
      oa[g] = __builtin_amdgcn_mfma_f32_16x16x32_bf16(pf, vf, oa[g], 0, 0, 0);
    }
  }

#pragma unroll
  for (int r = 0; r < 4; r++) {
    float inv = 1.0f / li[r];
    int row = qw + quad * 4 + r;
    bf16* dst = ao + ((size_t)b * Tn + row) * DIM + h * DH;
    dst[ 0 + lrow] = (bf16)(oa[0][r] * inv);
    dst[16 + lrow] = (bf16)(oa[1][r] * inv);
    dst[32 + lrow] = (bf16)(oa[2][r] * inv);
    dst[48 + lrow] = (bf16)(oa[3][r] * inv);
  }
}

// ---------------- launcher ----------------
extern "C" void kernel_launch(void* const* d_in, const int* in_sizes, int n_in,
                              void* d_out, int out_size, void* d_ws, size_t ws_size,
                              hipStream_t stream) {
  const float* x    = (const float*)d_in[0];
  const float* Wqkv = (const float*)d_in[1];
  const float* Wout = (const float*)d_in[2];
  float* out = (float*)d_out;
  char* ws = (char*)d_ws;

  bf16* xb    = (bf16*)(ws + 0);                 //  8,388,608 B
  bf16* wqkvT = (bf16*)(ws + 8388608);           //  6,291,456 B
  bf16* woutT = (bf16*)(ws + 14680064);          //  2,097,152 B
  bf16* qkv   = (bf16*)(ws + 16777216);          // 25,165,824 B
  bf16* vt    = (bf16*)(ws + 41943040);          //  8,388,608 B
  bf16* ao    = (bf16*)(ws + 50331648);          //  8,388,608 B  (total 56 MiB)

  k_f32_to_bf16<<<4096, 256, 0, stream>>>(x, xb, 1048576);
  k_transpose_w<<<dim3(96, 32), dim3(32, 8), 0, stream>>>(Wqkv, wqkvT, 1024, 3072);
  k_transpose_w<<<dim3(32, 32), dim3(32, 8), 0, stream>>>(Wout, woutT, 1024, 1024);
  k_gemm_bt<false><<<dim3(24, 32), 256, 0, stream>>>(xb, wqkvT, (void*)qkv, 4096, 3072, 1024);
  k_rope<<<8192, 256, 0, stream>>>(qkv);
  k_transpose_v<<<dim3(32, 2, 64), dim3(32, 8), 0, stream>>>(qkv, vt);
  k_attn<<<dim3(16, 64), 256, 0, stream>>>(qkv, vt, ao);
  k_gemm_bt<true><<<dim3(8, 32), 256, 0, stream>>>(ao, woutT, d_out, 4096, 1024, 1024);
  (void)out; (void)in_sizes; (void)n_in; (void)out_size; (void)ws_size;
}

// Round 2
// 194.279 us; speedup vs baseline: 1.2183x; 1.2183x over previous
//
#include <hip/hip_runtime.h>
#include <cstdint>
#include <cstddef>

typedef __bf16 bf16;
typedef __bf16 bf16x8 __attribute__((ext_vector_type(8)));
typedef float f32x4 __attribute__((ext_vector_type(4)));

#define DEVINL __device__ __forceinline__

static constexpr int Tn   = 1024;
static constexpr int DIM  = 1024;
static constexpr int NH   = 16;
static constexpr int DH   = 64;
static constexpr int QKVN = 3072;

DEVINL void g2l16(const void* g, void* l) {
  __builtin_amdgcn_global_load_lds(
      (const __attribute__((address_space(1))) void*)g,
      (__attribute__((address_space(3))) void*)l, 16, 0, 0);
}

// ---------------- pre/post utility kernels ----------------

__global__ void k_f32_to_bf16(const float* __restrict__ in, bf16* __restrict__ out, int n4) {
  int i = blockIdx.x * blockDim.x + threadIdx.x;
  if (i >= n4) return;
  float4 v = reinterpret_cast<const float4*>(in)[i];
  bf16 o[4] = {(bf16)v.x, (bf16)v.y, (bf16)v.z, (bf16)v.w};
  reinterpret_cast<uint2*>(out)[i] = *reinterpret_cast<uint2*>(o);
}

// W[K][N] f32 -> Wt[N][K] bf16   (block 32x8, grid (N/32, K/32))
__global__ void k_transpose_w(const float* __restrict__ in, bf16* __restrict__ out, int K, int N) {
  __shared__ float tile[32][33];
  int n0 = blockIdx.x * 32, k0 = blockIdx.y * 32;
  int tx = threadIdx.x, ty = threadIdx.y;
#pragma unroll
  for (int j = 0; j < 32; j += 8)
    tile[ty + j][tx] = in[(size_t)(k0 + ty + j) * N + n0 + tx];
  __syncthreads();
#pragma unroll
  for (int j = 0; j < 32; j += 8)
    out[(size_t)(n0 + ty + j) * K + k0 + tx] = (bf16)tile[tx][ty + j];
}

// RoPE in-place on q,k sections of qkv (B,T,3*1024) bf16. 2,097,152 threads, one pair each.
__global__ void k_rope(bf16* __restrict__ qkv) {
  int idx = blockIdx.x * 256 + threadIdx.x;
  int i = idx & 15;
  int h = (idx >> 4) & 15;
  int w = (idx >> 8) & 1;
  int t = (idx >> 9) & 1023;
  int b = idx >> 19;
  float inv = exp2f(-(float)(2 * i) * (13.287712379549449f / 32.0f));
  float ang = (float)t * inv;
  float sn, cs;
  sincosf(ang, &sn, &cs);
  size_t base = ((size_t)(b * Tn + t)) * QKVN + (size_t)w * DIM + h * DH + 2 * i;
  float x1 = (float)qkv[base], x2 = (float)qkv[base + 1];
  qkv[base]     = (bf16)(x1 * cs - x2 * sn);
  qkv[base + 1] = (bf16)(x2 * cs + x1 * sn);
}

// V section of qkv -> vt[b][h][d][t]  (block 32x8, grid (T/32, DH/32, B*NH))
__global__ void k_transpose_v(const bf16* __restrict__ qkv, bf16* __restrict__ vt) {
  __shared__ bf16 tile[32][33];
  int t0 = blockIdx.x * 32, d0 = blockIdx.y * 32;
  int bh = blockIdx.z;
  int b = bh >> 4, h = bh & 15;
  int tx = threadIdx.x, ty = threadIdx.y;
#pragma unroll
  for (int j = 0; j < 32; j += 8)
    tile[ty + j][tx] = qkv[((size_t)(b * Tn + t0 + ty + j)) * QKVN + 2 * DIM + h * DH + d0 + tx];
  __syncthreads();
#pragma unroll
  for (int j = 0; j < 32; j += 8)
    vt[((size_t)(bh * DH + d0 + ty + j)) * Tn + t0 + tx] = tile[tx][ty + j];
}

// ---------------- MFMA GEMM: C[M,N] = A[M,K] * Bt[N,K]^T ----------------
template <bool F32OUT>
__global__ __launch_bounds__(256) void k_gemm_bt(
    const bf16* __restrict__ A, const bf16* __restrict__ Bt,
    void* __restrict__ Cp, int M, int N, int K) {
  __shared__ bf16 As[128 * 64];
  __shared__ bf16 Bs[128 * 64];
  const int tid  = threadIdx.x;
  const int wave = tid >> 6, lane = tid & 63;
  const int lrow = lane & 15, quad = lane >> 4;
  const int m0 = blockIdx.y * 128, n0 = blockIdx.x * 128;
  const int wm = (wave >> 1) * 64, wn = (wave & 1) * 64;

  f32x4 acc[4][4];
#pragma unroll
  for (int mi = 0; mi < 4; mi++)
#pragma unroll
    for (int ni = 0; ni < 4; ni++) acc[mi][ni] = 0.f;

  for (int k0 = 0; k0 < K; k0 += 64) {
    __syncthreads();
#pragma unroll
    for (int i = 0; i < 4; i++) {
      int li = i * 256 + tid;
      int row = li >> 3, c = li & 7;
      int gc = c ^ (row & 7);
      g2l16(A + (size_t)(m0 + row) * K + k0 + gc * 8, As + li * 8);
    }
#pragma unroll
    for (int i = 0; i < 4; i++) {
      int li = i * 256 + tid;
      int row = li >> 3, c = li & 7;
      int gc = c ^ (row & 7);
      g2l16(Bt + (size_t)(n0 + row) * K + k0 + gc * 8, Bs + li * 8);
    }
    __syncthreads();
#pragma unroll
    for (int ki = 0; ki < 2; ki++) {
      bf16x8 af[4], bfr[4];
#pragma unroll
      for (int mi = 0; mi < 4; mi++) {
        int r = wm + mi * 16 + lrow;
        int pc = (ki * 4 + quad) ^ (r & 7);
        af[mi] = *reinterpret_cast<const bf16x8*>(As + r * 64 + pc * 8);
      }
#pragma unroll
      for (int ni = 0; ni < 4; ni++) {
        int r = wn + ni * 16 + lrow;
        int pc = (ki * 4 + quad) ^ (r & 7);
        bfr[ni] = *reinterpret_cast<const bf16x8*>(Bs + r * 64 + pc * 8);
      }
#pragma unroll
      for (int mi = 0; mi < 4; mi++)
#pragma unroll
        for (int ni = 0; ni < 4; ni++)
          acc[mi][ni] = __builtin_amdgcn_mfma_f32_16x16x32_bf16(af[mi], bfr[ni], acc[mi][ni], 0, 0, 0);
    }
  }

#pragma unroll
  for (int mi = 0; mi < 4; mi++)
#pragma unroll
    for (int ni = 0; ni < 4; ni++) {
      int col = n0 + wn + ni * 16 + lrow;
#pragma unroll
      for (int r = 0; r < 4; r++) {
        int row = m0 + wm + mi * 16 + quad * 4 + r;
        float v = acc[mi][ni][r];
        if (F32OUT)
          reinterpret_cast<float*>(Cp)[(size_t)row * N + col] = v;
        else
          reinterpret_cast<bf16*>(Cp)[(size_t)row * N + col] = (bf16)v;
      }
    }
}

// ---------------- causal flash attention, fixed-base softmax ----------------
// grid (T/64, B*NH), 256 threads = 4 waves; wave handles 16 q rows; 64-key tiles,
// double-buffered K/V in LDS. Softmax uses fixed base (exactly equivalent math:
// p = exp2(s), out = sum(p*v)/sum(p); s bounded ~|9| so no overflow possible).
__global__ __launch_bounds__(256) void k_attn(
    const bf16* __restrict__ qkv, const bf16* __restrict__ vt,
    bf16* __restrict__ ao) {
  __shared__ bf16 Ks[2][64 * 64];     // [key][d], 16B-chunk XOR swizzle by key&7
  __shared__ bf16 Vs[2][64 * 64];     // [d][key], chunk swizzle by d&7
  __shared__ bf16 Ps[4][16 * 64];     // per-wave P [m][key], chunk swizzle by m&7

  const int tid  = threadIdx.x;
  const int wave = tid >> 6, lane = tid & 63;
  const int lrow = lane & 15, quad = lane >> 4;
  const int bh = blockIdx.y, b = bh >> 4, h = bh & 15;
  const int q0 = blockIdx.x * 64;
  const int qw = q0 + wave * 16;
  const size_t qbase = (size_t)b * Tn * QKVN;

  // Q fragment, pre-scaled by 1/sqrt(dh)*log2(e)
  bf16x8 qf[2];
  {
    const bf16* qp = qkv + qbase + (size_t)(qw + lrow) * QKVN + h * DH;
    qf[0] = *reinterpret_cast<const bf16x8*>(qp + quad * 8);
    qf[1] = *reinterpret_cast<const bf16x8*>(qp + 32 + quad * 8);
    const float SC = 0.125f * 1.44269504088896f;
#pragma unroll
    for (int j = 0; j < 8; j++) {
      qf[0][j] = (bf16)((float)qf[0][j] * SC);
      qf[1][j] = (bf16)((float)qf[1][j] * SC);
    }
  }

  f32x4 oa[4];
#pragma unroll
  for (int g = 0; g < 4; g++) oa[g] = 0.f;
  float li[4] = {0.f, 0.f, 0.f, 0.f};

  const int ktiles = blockIdx.x + 1;

  // stage one 64-key tile of K and V into buffer `bufi`
  auto stage = [&](int k0, int bufi) {
#pragma unroll
    for (int i = 0; i < 2; i++) {
      int li2 = i * 256 + tid;
      int row = li2 >> 3, c = li2 & 7;
      int gc = c ^ (row & 7);
      g2l16(qkv + qbase + (size_t)(k0 + row) * QKVN + DIM + h * DH + gc * 8,
            &Ks[bufi][li2 * 8]);
      g2l16(vt + ((size_t)bh * DH + row) * Tn + k0 + gc * 8,
            &Vs[bufi][li2 * 8]);
    }
  };

  stage(0, 0);

  for (int kt = 0; kt < ktiles; kt++) {
    const int buf = kt & 1;
    __syncthreads();                       // tile kt resident; buf^1 free
    if (kt + 1 < ktiles) stage((kt + 1) << 6, buf ^ 1);  // overlaps compute

    const bf16* ks = Ks[buf];
    const bf16* vs = Vs[buf];

    // S = Q K^T  (4 key-groups of 16, K-dim 64 in two halves)
    f32x4 s[4];
#pragma unroll
    for (int g = 0; g < 4; g++) s[g] = 0.f;
#pragma unroll
    for (int kh = 0; kh < 2; kh++) {
      const int cX = ((kh * 4 + quad) ^ (lrow & 7)) << 3;
#pragma unroll
      for (int g = 0; g < 4; g++) {
        bf16x8 kf = *reinterpret_cast<const bf16x8*>(ks + (g * 16 + lrow) * 64 + cX);
        s[g] = __builtin_amdgcn_mfma_f32_16x16x32_bf16(qf[kh], kf, s[g], 0, 0, 0);
      }
    }

    // P = exp2(S) (fixed base); mask only in the diagonal tile
    const bool lastt = (kt == ktiles - 1);
#pragma unroll
    for (int g = 0; g < 4; g++) {
#pragma unroll
      for (int r = 0; r < 4; r++) {
        float p = exp2f(s[g][r]);
        if (lastt) {
          int kglob = (kt << 6) + g * 16 + lrow;
          int qi = qw + quad * 4 + r;
          p = (kglob <= qi) ? p : 0.f;
        }
        li[r] += p;
        int m = quad * 4 + r;
        int chunk = g * 2 + (lrow >> 3);
        Ps[wave][m * 64 + ((chunk ^ (m & 7)) << 3) + (lrow & 7)] = (bf16)p;
      }
    }

    // O += P V   (P from per-wave LDS, A-layout; V^T as B operand)
#pragma unroll
    for (int kh = 0; kh < 2; kh++) {
      const int cX = ((kh * 4 + quad) ^ (lrow & 7)) << 3;
      bf16x8 pf = *reinterpret_cast<const bf16x8*>(Ps[wave] + lrow * 64 + cX);
#pragma unroll
      for (int g = 0; g < 4; g++) {
        bf16x8 vf = *reinterpret_cast<const bf16x8*>(vs + (g * 16 + lrow) * 64 + cX);
        oa[g] = __builtin_amdgcn_mfma_f32_16x16x32_bf16(pf, vf, oa[g], 0, 0, 0);
      }
    }
  }

  // single final reduction of the softmax denominator (16 lanes of this quad)
#pragma unroll
  for (int r = 0; r < 4; r++) {
    li[r] += __shfl_xor(li[r], 1, 64);
    li[r] += __shfl_xor(li[r], 2, 64);
    li[r] += __shfl_xor(li[r], 4, 64);
    li[r] += __shfl_xor(li[r], 8, 64);
  }

#pragma unroll
  for (int r = 0; r < 4; r++) {
    float inv = 1.0f / li[r];
    int row = qw + quad * 4 + r;
    bf16* dst = ao + ((size_t)b * Tn + row) * DIM + h * DH;
    dst[ 0 + lrow] = (bf16)(oa[0][r] * inv);
    dst[16 + lrow] = (bf16)(oa[1][r] * inv);
    dst[32 + lrow] = (bf16)(oa[2][r] * inv);
    dst[48 + lrow] = (bf16)(oa[3][r] * inv);
  }
}

// ---------------- launcher ----------------
extern "C" void kernel_launch(void* const* d_in, const int* in_sizes, int n_in,
                              void* d_out, int out_size, void* d_ws, size_t ws_size,
                              hipStream_t stream) {
  const float* x    = (const float*)d_in[0];
  const float* Wqkv = (const float*)d_in[1];
  const float* Wout = (const float*)d_in[2];
  char* ws = (char*)d_ws;

  bf16* xb    = (bf16*)(ws + 0);
  bf16* wqkvT = (bf16*)(ws + 8388608);
  bf16* woutT = (bf16*)(ws + 14680064);
  bf16* qkv   = (bf16*)(ws + 16777216);
  bf16* vt    = (bf16*)(ws + 41943040);
  bf16* ao    = (bf16*)(ws + 50331648);

  k_f32_to_bf16<<<4096, 256, 0, stream>>>(x, xb, 1048576);
  k_transpose_w<<<dim3(96, 32), dim3(32, 8), 0, stream>>>(Wqkv, wqkvT, 1024, 3072);
  k_transpose_w<<<dim3(32, 32), dim3(32, 8), 0, stream>>>(Wout, woutT, 1024, 1024);
  k_gemm_bt<false><<<dim3(24, 32), 256, 0, stream>>>(xb, wqkvT, (void*)qkv, 4096, 3072, 1024);
  k_rope<<<8192, 256, 0, stream>>>(qkv);
  k_transpose_v<<<dim3(32, 2, 64), dim3(32, 8), 0, stream>>>(qkv, vt);
  k_attn<<<dim3(16, 64), 256, 0, stream>>>(qkv, vt, ao);
  k_gemm_bt<true><<<dim3(8, 32), 256, 0, stream>>>(ao, woutT, d_out, 4096, 1024, 1024);
  (void)in_sizes; (void)n_in; (void)out_size; (void)ws_size;
}

// Round 4
// 176.156 us; speedup vs baseline: 1.3436x; 1.1029x over previous
//
#include <hip/hip_runtime.h>
#include <cstdint>
#include <cstddef>

typedef __bf16 bf16;
typedef __bf16 bf16x4 __attribute__((ext_vector_type(4)));
typedef __bf16 bf16x8 __attribute__((ext_vector_type(8)));
typedef float f32x4 __attribute__((ext_vector_type(4)));

#define DEVINL __device__ __forceinline__

static constexpr int Tn   = 1024;
static constexpr int DIM  = 1024;
static constexpr int NH   = 16;
static constexpr int DH   = 64;
static constexpr int QKVN = 3072;

DEVINL void g2l16(const void* g, void* l) {
  __builtin_amdgcn_global_load_lds(
      (const __attribute__((address_space(1))) void*)g,
      (__attribute__((address_space(3))) void*)l, 16, 0, 0);
}

// ---------------- pre/post utility kernels ----------------

__global__ void k_f32_to_bf16(const float* __restrict__ in, bf16* __restrict__ out, int n4) {
  int i = blockIdx.x * blockDim.x + threadIdx.x;
  if (i >= n4) return;
  float4 v = reinterpret_cast<const float4*>(in)[i];
  bf16 o[4] = {(bf16)v.x, (bf16)v.y, (bf16)v.z, (bf16)v.w};
  reinterpret_cast<uint2*>(out)[i] = *reinterpret_cast<uint2*>(o);
}

// W[K][N] f32 -> Wt[N][K] bf16   (block 32x8, grid (N/32, K/32))
__global__ void k_transpose_w(const float* __restrict__ in, bf16* __restrict__ out, int K, int N) {
  __shared__ float tile[32][33];
  int n0 = blockIdx.x * 32, k0 = blockIdx.y * 32;
  int tx = threadIdx.x, ty = threadIdx.y;
#pragma unroll
  for (int j = 0; j < 32; j += 8)
    tile[ty + j][tx] = in[(size_t)(k0 + ty + j) * N + n0 + tx];
  __syncthreads();
#pragma unroll
  for (int j = 0; j < 32; j += 8)
    out[(size_t)(n0 + ty + j) * K + k0 + tx] = (bf16)tile[tx][ty + j];
}

// RoPE in-place on q,k sections of qkv (B,T,3*1024) bf16.
__global__ void k_rope(bf16* __restrict__ qkv) {
  int idx = blockIdx.x * 256 + threadIdx.x;
  int i = idx & 15;
  int h = (idx >> 4) & 15;
  int w = (idx >> 8) & 1;
  int t = (idx >> 9) & 1023;
  int b = idx >> 19;
  float inv = exp2f(-(float)(2 * i) * (13.287712379549449f / 32.0f));
  float ang = (float)t * inv;
  float sn, cs;
  sincosf(ang, &sn, &cs);
  size_t base = ((size_t)(b * Tn + t)) * QKVN + (size_t)w * DIM + h * DH + 2 * i;
  float x1 = (float)qkv[base], x2 = (float)qkv[base + 1];
  qkv[base]     = (bf16)(x1 * cs - x2 * sn);
  qkv[base + 1] = (bf16)(x2 * cs + x1 * sn);
}

// V section of qkv -> vt[b][h][d][t]  (block 32x8, grid (T/32, DH/32, B*NH))
__global__ void k_transpose_v(const bf16* __restrict__ qkv, bf16* __restrict__ vt) {
  __shared__ bf16 tile[32][33];
  int t0 = blockIdx.x * 32, d0 = blockIdx.y * 32;
  int bh = blockIdx.z;
  int b = bh >> 4, h = bh & 15;
  int tx = threadIdx.x, ty = threadIdx.y;
#pragma unroll
  for (int j = 0; j < 32; j += 8)
    tile[ty + j][tx] = qkv[((size_t)(b * Tn + t0 + ty + j)) * QKVN + 2 * DIM + h * DH + d0 + tx];
  __syncthreads();
#pragma unroll
  for (int j = 0; j < 32; j += 8)
    vt[((size_t)(bh * DH + d0 + ty + j)) * Tn + t0 + tx] = tile[tx][ty + j];
}

// ---------------- MFMA GEMM: C[M,N] = A[M,K] * Bt[N,K]^T ----------------
template <bool F32OUT>
__global__ __launch_bounds__(256) void k_gemm_bt(
    const bf16* __restrict__ A, const bf16* __restrict__ Bt,
    void* __restrict__ Cp, int M, int N, int K) {
  __shared__ bf16 As[128 * 64];
  __shared__ bf16 Bs[128 * 64];
  const int tid  = threadIdx.x;
  const int wave = tid >> 6, lane = tid & 63;
  const int lrow = lane & 15, quad = lane >> 4;
  const int m0 = blockIdx.y * 128, n0 = blockIdx.x * 128;
  const int wm = (wave >> 1) * 64, wn = (wave & 1) * 64;

  f32x4 acc[4][4];
#pragma unroll
  for (int mi = 0; mi < 4; mi++)
#pragma unroll
    for (int ni = 0; ni < 4; ni++) acc[mi][ni] = 0.f;

  for (int k0 = 0; k0 < K; k0 += 64) {
    __syncthreads();
#pragma unroll
    for (int i = 0; i < 4; i++) {
      int li = i * 256 + tid;
      int row = li >> 3, c = li & 7;
      int gc = c ^ (row & 7);
      g2l16(A + (size_t)(m0 + row) * K + k0 + gc * 8, As + li * 8);
    }
#pragma unroll
    for (int i = 0; i < 4; i++) {
      int li = i * 256 + tid;
      int row = li >> 3, c = li & 7;
      int gc = c ^ (row & 7);
      g2l16(Bt + (size_t)(n0 + row) * K + k0 + gc * 8, Bs + li * 8);
    }
    __syncthreads();
#pragma unroll
    for (int ki = 0; ki < 2; ki++) {
      bf16x8 af[4], bfr[4];
#pragma unroll
      for (int mi = 0; mi < 4; mi++) {
        int r = wm + mi * 16 + lrow;
        int pc = (ki * 4 + quad) ^ (r & 7);
        af[mi] = *reinterpret_cast<const bf16x8*>(As + r * 64 + pc * 8);
      }
#pragma unroll
      for (int ni = 0; ni < 4; ni++) {
        int r = wn + ni * 16 + lrow;
        int pc = (ki * 4 + quad) ^ (r & 7);
        bfr[ni] = *reinterpret_cast<const bf16x8*>(Bs + r * 64 + pc * 8);
      }
#pragma unroll
      for (int mi = 0; mi < 4; mi++)
#pragma unroll
        for (int ni = 0; ni < 4; ni++)
          acc[mi][ni] = __builtin_amdgcn_mfma_f32_16x16x32_bf16(af[mi], bfr[ni], acc[mi][ni], 0, 0, 0);
    }
  }

#pragma unroll
  for (int mi = 0; mi < 4; mi++)
#pragma unroll
    for (int ni = 0; ni < 4; ni++) {
      int col = n0 + wn + ni * 16 + lrow;
#pragma unroll
      for (int r = 0; r < 4; r++) {
        int row = m0 + wm + mi * 16 + quad * 4 + r;
        float v = acc[mi][ni][r];
        if (F32OUT)
          reinterpret_cast<float*>(Cp)[(size_t)row * N + col] = v;
        else
          reinterpret_cast<bf16*>(Cp)[(size_t)row * N + col] = (bf16)v;
      }
    }
}

// ---------------- causal flash attention ----------------
// Triangle-paired: block j handles q-tiles j and 15-j (uniform 17 compute units).
// grid (8, B*NH), 256 threads = 4 waves; each wave owns 16 q rows of EACH tile.
// Fixed-base softmax (exactly equivalent; |s|<~9 so exp2 can't overflow).
// S^T via swapped MFMA operands -> lane holds 4 consecutive keys -> packed
// ds_write_b64 P stores and in-lane denominator accumulation.
// NOTE: in S^T orientation the lane's q index is lrow WITHIN THE WAVE SLICE;
// absolute q-within-tile = wave*16 + lrow. R3 bug was masking kl<=lrow.
__global__ __launch_bounds__(256) void k_attn(
    const bf16* __restrict__ qkv, const bf16* __restrict__ vt,
    bf16* __restrict__ ao) {
  __shared__ bf16 Ks[2][64 * 64];     // [key][d], 16B-chunk XOR swizzle by key&7
  __shared__ bf16 Vs[2][64 * 64];     // [d][key], chunk swizzle by d&7
  __shared__ bf16 Ps[8][16 * 64];     // [wave*2+set][q][key], chunk swizzle by q&7

  const int tid  = threadIdx.x;
  const int wave = tid >> 6, lane = tid & 63;
  const int lrow = lane & 15, quad = lane >> 4;
  const int bh = blockIdx.y, b = bh >> 4, h = bh & 15;
  const int jn = blockIdx.x;          // near q-tile (0..7)
  const int jf = 15 - jn;             // far q-tile (8..15)
  const int qwf = jf * 64 + wave * 16;
  const int qwn = jn * 64 + wave * 16;
  const size_t qbase = (size_t)b * Tn * QKVN;

  // Q fragments for both q-sets, pre-scaled by 1/sqrt(dh)*log2(e)
  bf16x8 qff[2], qfn[2];
  {
    const float SC = 0.125f * 1.44269504088896f;
    const bf16* qpf = qkv + qbase + (size_t)(qwf + lrow) * QKVN + h * DH;
    const bf16* qpn = qkv + qbase + (size_t)(qwn + lrow) * QKVN + h * DH;
    qff[0] = *reinterpret_cast<const bf16x8*>(qpf + quad * 8);
    qff[1] = *reinterpret_cast<const bf16x8*>(qpf + 32 + quad * 8);
    qfn[0] = *reinterpret_cast<const bf16x8*>(qpn + quad * 8);
    qfn[1] = *reinterpret_cast<const bf16x8*>(qpn + 32 + quad * 8);
#pragma unroll
    for (int j = 0; j < 8; j++) {
      qff[0][j] = (bf16)((float)qff[0][j] * SC);
      qff[1][j] = (bf16)((float)qff[1][j] * SC);
      qfn[0][j] = (bf16)((float)qfn[0][j] * SC);
      qfn[1][j] = (bf16)((float)qfn[1][j] * SC);
    }
  }

  f32x4 oaf[4], oan[4];
#pragma unroll
  for (int g = 0; g < 4; g++) { oaf[g] = 0.f; oan[g] = 0.f; }
  float lif = 0.f, lin = 0.f;

  const int ntiles = jf + 1;   // union of key tiles needed by both q-sets

  auto stage = [&](int k0, int bufi) {
#pragma unroll
    for (int i = 0; i < 2; i++) {
      int li2 = i * 256 + tid;
      int row = li2 >> 3, c = li2 & 7;
      int gc = c ^ (row & 7);
      g2l16(qkv + qbase + (size_t)(k0 + row) * QKVN + DIM + h * DH + gc * 8,
            &Ks[bufi][li2 * 8]);
      g2l16(vt + ((size_t)bh * DH + row) * Tn + k0 + gc * 8,
            &Vs[bufi][li2 * 8]);
    }
  };

  // one 64-key tile for one q-set: S^T = K Q^T, exp, packed P store, O += P V
  auto unit = [&](const bf16* ks, const bf16* vs, bf16x8 (&qf)[2], f32x4 (&oa)[4],
                  float& li, int pi, bool diag) {
    f32x4 s[4];
#pragma unroll
    for (int g = 0; g < 4; g++) s[g] = 0.f;
#pragma unroll
    for (int kh = 0; kh < 2; kh++) {
      const int cX = ((kh * 4 + quad) ^ (lrow & 7)) << 3;
#pragma unroll
      for (int g = 0; g < 4; g++) {
        bf16x8 kf = *reinterpret_cast<const bf16x8*>(ks + (g * 16 + lrow) * 64 + cX);
        s[g] = __builtin_amdgcn_mfma_f32_16x16x32_bf16(kf, qf[kh], s[g], 0, 0, 0);
      }
    }
    // lane holds S^T[key = 16g+4*quad+r][q = wave*16 + lrow]
    float psum = 0.f;
    const int qrel = wave * 16 + lrow;   // q within the 64-row q-tile
#pragma unroll
    for (int g = 0; g < 4; g++) {
      bf16x4 pk;
#pragma unroll
      for (int r = 0; r < 4; r++) {
        float p = exp2f(s[g][r]);
        if (diag) {
          int kl = g * 16 + quad * 4 + r;   // key within tile
          p = (kl <= qrel) ? p : 0.f;       // R3 bug: compared vs lrow only
        }
        psum += p;
        pk[r] = (bf16)p;
      }
      int chunk = 2 * g + (quad >> 1);
      *reinterpret_cast<bf16x4*>(
          Ps[pi] + lrow * 64 + ((chunk ^ (lrow & 7)) << 3) + 4 * (quad & 1)) = pk;
    }
    li += psum;
#pragma unroll
    for (int kh = 0; kh < 2; kh++) {
      const int cX = ((kh * 4 + quad) ^ (lrow & 7)) << 3;
      bf16x8 pf = *reinterpret_cast<const bf16x8*>(Ps[pi] + lrow * 64 + cX);
#pragma unroll
      for (int g = 0; g < 4; g++) {
        bf16x8 vf = *reinterpret_cast<const bf16x8*>(vs + (g * 16 + lrow) * 64 + cX);
        oa[g] = __builtin_amdgcn_mfma_f32_16x16x32_bf16(pf, vf, oa[g], 0, 0, 0);
      }
    }
  };

  stage(0, 0);

  for (int kt = 0; kt < ntiles; kt++) {
    const int buf = kt & 1;
    __syncthreads();                                   // tile kt resident
    if (kt + 1 < ntiles) stage((kt + 1) << 6, buf ^ 1);  // overlaps compute

    const bf16* ks = Ks[buf];
    const bf16* vs = Vs[buf];

    unit(ks, vs, qff, oaf, lif, wave * 2 + 0, kt == jf);   // far tile: always active
    if (kt <= jn)
      unit(ks, vs, qfn, oan, lin, wave * 2 + 1, kt == jn); // near tile
  }

  // denominators: in-lane partials -> reduce across quads, then distribute per row
  lif += __shfl_xor(lif, 16, 64); lif += __shfl_xor(lif, 32, 64);
  lin += __shfl_xor(lin, 16, 64); lin += __shfl_xor(lin, 32, 64);

#pragma unroll
  for (int r = 0; r < 4; r++) {
    int m = quad * 4 + r;
    float invf = 1.0f / __shfl(lif, m, 64);
    float invn = 1.0f / __shfl(lin, m, 64);
    bf16* dstf = ao + ((size_t)b * Tn + qwf + m) * DIM + h * DH;
    bf16* dstn = ao + ((size_t)b * Tn + qwn + m) * DIM + h * DH;
    dstf[ 0 + lrow] = (bf16)(oaf[0][r] * invf);
    dstf[16 + lrow] = (bf16)(oaf[1][r] * invf);
    dstf[32 + lrow] = (bf16)(oaf[2][r] * invf);
    dstf[48 + lrow] = (bf16)(oaf[3][r] * invf);
    dstn[ 0 + lrow] = (bf16)(oan[0][r] * invn);
    dstn[16 + lrow] = (bf16)(oan[1][r] * invn);
    dstn[32 + lrow] = (bf16)(oan[2][r] * invn);
    dstn[48 + lrow] = (bf16)(oan[3][r] * invn);
  }
}

// ---------------- launcher ----------------
extern "C" void kernel_launch(void* const* d_in, const int* in_sizes, int n_in,
                              void* d_out, int out_size, void* d_ws, size_t ws_size,
                              hipStream_t stream) {
  const float* x    = (const float*)d_in[0];
  const float* Wqkv = (const float*)d_in[1];
  const float* Wout = (const float*)d_in[2];
  char* ws = (char*)d_ws;

  bf16* xb    = (bf16*)(ws + 0);
  bf16* wqkvT = (bf16*)(ws + 8388608);
  bf16* woutT = (bf16*)(ws + 14680064);
  bf16* qkv   = (bf16*)(ws + 16777216);
  bf16* vt    = (bf16*)(ws + 41943040);
  bf16* ao    = (bf16*)(ws + 50331648);

  k_f32_to_bf16<<<4096, 256, 0, stream>>>(x, xb, 1048576);
  k_transpose_w<<<dim3(96, 32), dim3(32, 8), 0, stream>>>(Wqkv, wqkvT, 1024, 3072);
  k_transpose_w<<<dim3(32, 32), dim3(32, 8), 0, stream>>>(Wout, woutT, 1024, 1024);
  k_gemm_bt<false><<<dim3(24, 32), 256, 0, stream>>>(xb, wqkvT, (void*)qkv, 4096, 3072, 1024);
  k_rope<<<8192, 256, 0, stream>>>(qkv);
  k_transpose_v<<<dim3(32, 2, 64), dim3(32, 8), 0, stream>>>(qkv, vt);
  k_attn<<<dim3(8, 64), 256, 0, stream>>>(qkv, vt, ao);
  k_gemm_bt<true><<<dim3(8, 32), 256, 0, stream>>>(ao, woutT, d_out, 4096, 1024, 1024);
  (void)in_sizes; (void)n_in; (void)out_size; (void)ws_size;
}